// Round 1
// baseline (338.722 us; speedup 1.0000x reference)
//
#include <hip/hip_runtime.h>

// ---------------------------------------------------------------------------
// RoPE Multi-Headed Attention (quirky softmax(exp(qr·kr)/den) variant)
// B=2, S=2048, D=1024, H=16, HD=64
// ---------------------------------------------------------------------------

#define Bn 2
#define Sn 2048
#define Dn 1024
#define Hn 16
#define HDn 64
#define Mn (Bn * Sn)   // 4096

typedef __attribute__((ext_vector_type(8))) short bf16x8;
typedef __attribute__((ext_vector_type(8))) unsigned short u16x8;
typedef __attribute__((ext_vector_type(4))) float f32x4;

#define MFMA(a, b, c) __builtin_amdgcn_mfma_f32_16x16x32_bf16(a, b, c, 0, 0, 0)

__device__ __forceinline__ unsigned short f2bf(float f) {
  unsigned int u = __builtin_bit_cast(unsigned int, f);
  u = (u + 0x7fffu + ((u >> 16) & 1u)) >> 16;
  return (unsigned short)u;
}
__device__ __forceinline__ float bf2f(unsigned short u) {
  return __builtin_bit_cast(float, (unsigned int)u << 16);
}

// ---------------------------------------------------------------------------
// 1. Weight transpose+convert: W[k][n] f32 -> Wt[n][k] bf16   (4 weights)
// ---------------------------------------------------------------------------
__global__ __launch_bounds__(256) void k_wtrans(
    const float* __restrict__ W0, const float* __restrict__ W1,
    const float* __restrict__ W2, const float* __restrict__ W3,
    unsigned short* __restrict__ O0, unsigned short* __restrict__ O1,
    unsigned short* __restrict__ O2, unsigned short* __restrict__ O3) {
  __shared__ float t[64][65];
  int which = blockIdx.z;
  const float* W = (which == 0) ? W0 : (which == 1) ? W1 : (which == 2) ? W2 : W3;
  unsigned short* O = (which == 0) ? O0 : (which == 1) ? O1 : (which == 2) ? O2 : O3;
  int kb = blockIdx.x * 64, nb = blockIdx.y * 64;
  int tid = threadIdx.x;
#pragma unroll
  for (int rep = 0; rep < 16; ++rep) {
    int e = rep * 256 + tid;
    int k = e >> 6, n = e & 63;
    t[k][n] = W[(kb + k) * Dn + nb + n];
  }
  __syncthreads();
#pragma unroll
  for (int rep = 0; rep < 16; ++rep) {
    int e = rep * 256 + tid;
    int n = e >> 6, k = e & 63;
    O[(nb + n) * Dn + kb + k] = f2bf(t[k][n]);
  }
}

// ---------------------------------------------------------------------------
// 2. GEMM: C[m][n] = A[m][:] . Wt[n][:] + bias[n]
//    A: f32 [4096 x 1024] row-major (converted to bf16 during staging)
//    Wt: bf16 [1024 x 1024] (pre-transposed, row n holds column n of W)
//    MODE 0: out bf16 at [b,h,s,hd] layout (projections)
//    MODE 1: out f32 row-major [m][n] (final output)
// Block: 256 thr (4 waves), C-tile 128x128, wave tile 64x64, K-step 64.
// ---------------------------------------------------------------------------
template <int MODE>
__global__ __launch_bounds__(256) void k_gemm(const float* __restrict__ A,
                                              const unsigned short* __restrict__ Wt,
                                              const float* __restrict__ bias,
                                              void* __restrict__ out) {
  __shared__ unsigned short Al[128][72];
  __shared__ unsigned short Bl[128][72];
  int tid = threadIdx.x;
  int wave = tid >> 6, lane = tid & 63, g = lane >> 4, li = lane & 15;
  int mbase = blockIdx.x * 128, nbase = blockIdx.y * 128;
  int wm = wave >> 1, wn = wave & 1;

  f32x4 acc[4][4];
#pragma unroll
  for (int i = 0; i < 4; ++i)
#pragma unroll
    for (int j = 0; j < 4; ++j) acc[i][j] = (f32x4){0.f, 0.f, 0.f, 0.f};

  float bv[4];
#pragma unroll
  for (int nt = 0; nt < 4; ++nt) bv[nt] = bias[nbase + wn * 64 + nt * 16 + li];

  int srow = tid >> 1, scs = (tid & 1) * 32;

  for (int kb = 0; kb < Dn; kb += 64) {
    __syncthreads();
    // stage A (f32 -> bf16)
    const float* Ap = A + (size_t)(mbase + srow) * Dn + kb + scs;
#pragma unroll
    for (int i = 0; i < 4; ++i) {
      float4 v0 = *(const float4*)(Ap + i * 8);
      float4 v1 = *(const float4*)(Ap + i * 8 + 4);
      u16x8 pk;
      pk[0] = f2bf(v0.x); pk[1] = f2bf(v0.y); pk[2] = f2bf(v0.z); pk[3] = f2bf(v0.w);
      pk[4] = f2bf(v1.x); pk[5] = f2bf(v1.y); pk[6] = f2bf(v1.z); pk[7] = f2bf(v1.w);
      *(u16x8*)&Al[srow][scs + i * 8] = pk;
    }
    // stage B (bf16 copy)
    const unsigned short* Bp = Wt + (size_t)(nbase + srow) * Dn + kb + scs;
#pragma unroll
    for (int i = 0; i < 4; ++i) {
      *(u16x8*)&Bl[srow][scs + i * 8] = *(const u16x8*)(Bp + i * 8);
    }
    __syncthreads();

#pragma unroll
    for (int kc = 0; kc < 2; ++kc) {
      bf16x8 af[4], bf[4];
#pragma unroll
      for (int mt = 0; mt < 4; ++mt)
        af[mt] = *(const bf16x8*)&Al[wm * 64 + mt * 16 + li][kc * 32 + g * 8];
#pragma unroll
      for (int nt = 0; nt < 4; ++nt)
        bf[nt] = *(const bf16x8*)&Bl[wn * 64 + nt * 16 + li][kc * 32 + g * 8];
#pragma unroll
      for (int mt = 0; mt < 4; ++mt)
#pragma unroll
        for (int nt = 0; nt < 4; ++nt)
          acc[mt][nt] = MFMA(af[mt], bf[nt], acc[mt][nt]);
    }
  }

  // epilogue
#pragma unroll
  for (int mt = 0; mt < 4; ++mt) {
#pragma unroll
    for (int nt = 0; nt < 4; ++nt) {
      int n = nbase + wn * 64 + nt * 16 + li;
#pragma unroll
      for (int r = 0; r < 4; ++r) {
        int m = mbase + wm * 64 + mt * 16 + 4 * g + r;
        float v = acc[mt][nt][r] + bv[nt];
        if (MODE == 0) {
          int b = m >> 11, s = m & (Sn - 1);
          int h = n >> 6, hd = n & 63;
          ((unsigned short*)out)[(((size_t)(b * Hn + h)) * Sn + s) * HDn + hd] = f2bf(v);
        } else {
          ((float*)out)[(size_t)m * Dn + n] = v;
        }
      }
    }
  }
}

// ---------------------------------------------------------------------------
// 3. RoPE: interleaved pairs, base 1000. In/out bf16, layout [b,h,s,hd].
//    Processes both Q and K tensors (tensor = gid high bit).
// ---------------------------------------------------------------------------
__global__ __launch_bounds__(256) void k_rope(const unsigned short* __restrict__ Qb,
                                              const unsigned short* __restrict__ Kb,
                                              unsigned short* __restrict__ Qr,
                                              unsigned short* __restrict__ Kr) {
  int gid = blockIdx.x * 256 + threadIdx.x;  // 2*2*16*2048*8 = 1,048,576
  int chunk = gid & 7;
  int rowi = gid >> 3;           // 0..131071
  int tensor = rowi >> 16;       // 65536 rows per tensor
  int rem = rowi & 65535;        // (b*H+h)*S + s
  int s = rem & (Sn - 1);
  const unsigned short* src = tensor ? Kb : Qb;
  unsigned short* dst = tensor ? Kr : Qr;
  size_t addr = (size_t)rem * HDn + chunk * 8;
  u16x8 v = *(const u16x8*)(src + addr);
  u16x8 o;
#pragma unroll
  for (int p = 0; p < 4; ++p) {
    int i = chunk * 4 + p;  // pair index 0..31
    float theta = powf(1000.f, -(2.f * (float)i) / 64.f);
    float pm = (float)s * theta;
    float c = cosf(pm), sn = sinf(pm);
    float x0 = bf2f(v[2 * p]), x1 = bf2f(v[2 * p + 1]);
    o[2 * p] = f2bf(x0 * c - x1 * sn);
    o[2 * p + 1] = f2bf(x1 * c + x0 * sn);
  }
  *(u16x8*)(dst + addr) = o;
}

// ---------------------------------------------------------------------------
// 4. V transpose: Vb[b,h,s,hd] -> Vt[b,h,hd,s]   (bf16)
// ---------------------------------------------------------------------------
__global__ __launch_bounds__(256) void k_vtrans(const unsigned short* __restrict__ Vb,
                                                unsigned short* __restrict__ Vt) {
  __shared__ unsigned short t[64][65];
  int bh = blockIdx.y;
  int sb = blockIdx.x * 64;
  int tid = threadIdx.x;
#pragma unroll
  for (int rep = 0; rep < 16; ++rep) {
    int e = rep * 256 + tid;
    int sl = e >> 6, hd = e & 63;
    t[sl][hd] = Vb[((size_t)bh * Sn + sb + sl) * HDn + hd];
  }
  __syncthreads();
#pragma unroll
  for (int rep = 0; rep < 16; ++rep) {
    int e = rep * 256 + tid;
    int hd = e >> 6, sl = e & 63;
    Vt[((size_t)bh * HDn + hd) * Sn + sb + sl] = t[sl][hd];
  }
}

// ---------------------------------------------------------------------------
// 5. Attention. Block = 4 waves x 16 q-rows = 64 q rows; grid (S/64, B*H).
// Pass A (all k): den = sum exp(q.k/8); M = max_{k<=q} (qr.kr/8)
// Pass B (causal k): w = exp(exp(srope/8 - L) - exp(M - L)); Z += w*V; W += w
// out z = Z/W  -> f32 [b,s,h,hd]
// ---------------------------------------------------------------------------
__global__ __launch_bounds__(256) void k_attn(const unsigned short* __restrict__ Qr,
                                              const unsigned short* __restrict__ Kr,
                                              const unsigned short* __restrict__ Qb,
                                              const unsigned short* __restrict__ Kb,
                                              const unsigned short* __restrict__ Vt,
                                              float* __restrict__ Z) {
  __shared__ unsigned short K1[64][72];      // Kr tile (rows = k, cols = hd)
  __shared__ unsigned short K2[64][72];      // Kb tile (pass A) / Vt tile [hd][k] (pass B)
  __shared__ unsigned short Pl[4][16][72];   // per-wave P tile [q_local][k_local]

  int tid = threadIdx.x;
  int wave = tid >> 6, lane = tid & 63, g = lane >> 4, li = lane & 15;
  int qt = blockIdx.x, bh = blockIdx.y;
  int qbase = qt * 64;
  int qw = qbase + wave * 16;
  size_t kvbase = (size_t)bh * Sn * HDn;  // same for [b,h,s,hd] and [b,h,hd,s]

  // Q fragments (A operand): lane row = li, dims 8*g..+7 per 32-chunk
  bf16x8 qrf[2], qbf[2];
#pragma unroll
  for (int kc = 0; kc < 2; ++kc) {
    size_t a = kvbase + (size_t)(qw + li) * HDn + kc * 32 + g * 8;
    qrf[kc] = *(const bf16x8*)(Qr + a);
    qbf[kc] = *(const bf16x8*)(Qb + a);
  }

  int srow = tid >> 2, scol = tid & 3;

  // ------------------- PASS A -------------------
  float densum[4] = {0.f, 0.f, 0.f, 0.f};
  float mx[4] = {-1e30f, -1e30f, -1e30f, -1e30f};

  for (int kb = 0; kb < Sn; kb += 64) {
    __syncthreads();
#pragma unroll
    for (int cc = 0; cc < 2; ++cc) {
      int c = scol + cc * 4;
      *(u16x8*)&K1[srow][c * 8] = *(const u16x8*)(Kr + kvbase + (size_t)(kb + srow) * HDn + c * 8);
      *(u16x8*)&K2[srow][c * 8] = *(const u16x8*)(Kb + kvbase + (size_t)(kb + srow) * HDn + c * 8);
    }
    __syncthreads();

#pragma unroll
    for (int nt = 0; nt < 4; ++nt) {
      f32x4 acc = (f32x4){0.f, 0.f, 0.f, 0.f};
      f32x4 acc2 = (f32x4){0.f, 0.f, 0.f, 0.f};
#pragma unroll
      for (int kc = 0; kc < 2; ++kc) {
        bf16x8 krf = *(const bf16x8*)&K1[nt * 16 + li][kc * 32 + g * 8];
        bf16x8 kbf = *(const bf16x8*)&K2[nt * 16 + li][kc * 32 + g * 8];
        acc = MFMA(qrf[kc], krf, acc);
        acc2 = MFMA(qbf[kc], kbf, acc2);
      }
      int kg = kb + nt * 16 + li;
#pragma unroll
      for (int r = 0; r < 4; ++r) {
        densum[r] += __expf(acc2[r] * 0.125f);
        if (kg <= qw + 4 * g + r) mx[r] = fmaxf(mx[r], acc[r] * 0.125f);
      }
    }
  }

  // reduce across the 16 lanes of each quarter-wave group
  float Lr[4], am[4];
#pragma unroll
  for (int r = 0; r < 4; ++r) {
    float d = densum[r], m = mx[r];
#pragma unroll
    for (int off = 1; off < 16; off <<= 1) {
      d += __shfl_xor(d, off);
      m = fmaxf(m, __shfl_xor(m, off));
    }
    Lr[r] = __logf(d);
    am[r] = __expf(m - Lr[r]);  // max of a over causal k
  }

  // ------------------- PASS B -------------------
  f32x4 accz[4];
#pragma unroll
  for (int n2 = 0; n2 < 4; ++n2) accz[n2] = (f32x4){0.f, 0.f, 0.f, 0.f};
  float wsum[4] = {0.f, 0.f, 0.f, 0.f};

  for (int kb = 0; kb < qbase + 64; kb += 64) {
    __syncthreads();
#pragma unroll
    for (int cc = 0; cc < 2; ++cc) {
      int c = scol + cc * 4;
      *(u16x8*)&K1[srow][c * 8] = *(const u16x8*)(Kr + kvbase + (size_t)(kb + srow) * HDn + c * 8);
      // Vt tile: rows = hd, cols = k
      *(u16x8*)&K2[srow][c * 8] = *(const u16x8*)(Vt + kvbase + (size_t)srow * Sn + kb + c * 8);
    }
    __syncthreads();

#pragma unroll
    for (int nt = 0; nt < 4; ++nt) {
      f32x4 acc = (f32x4){0.f, 0.f, 0.f, 0.f};
#pragma unroll
      for (int kc = 0; kc < 2; ++kc) {
        bf16x8 krf = *(const bf16x8*)&K1[nt * 16 + li][kc * 32 + g * 8];
        acc = MFMA(qrf[kc], krf, acc);
      }
      int kg = kb + nt * 16 + li;
#pragma unroll
      for (int r = 0; r < 4; ++r) {
        float a = __expf(acc[r] * 0.125f - Lr[r]);
        float w = (kg <= qw + 4 * g + r) ? __expf(a - am[r]) : 0.f;
        wsum[r] += w;
        Pl[wave][4 * g + r][nt * 16 + li] = f2bf(w);
      }
    }
    __syncthreads();  // P visible (also orders K2 reuse; cheap insurance)

    // PV: Zw[16q x 64hd] += P[16 x 64] * V[64 x 64hd]
#pragma unroll
    for (int kc = 0; kc < 2; ++kc) {
      bf16x8 pa = *(const bf16x8*)&Pl[wave][li][kc * 32 + g * 8];
#pragma unroll
      for (int n2 = 0; n2 < 4; ++n2) {
        bf16x8 vb = *(const bf16x8*)&K2[n2 * 16 + li][kc * 32 + g * 8];
        accz[n2] = MFMA(pa, vb, accz[n2]);
      }
    }
  }

  // normalize + write z as f32 [b, s, h, hd]
#pragma unroll
  for (int r = 0; r < 4; ++r) {
    float w = wsum[r];
#pragma unroll
    for (int off = 1; off < 16; off <<= 1) w += __shfl_xor(w, off);
    wsum[r] = w;
  }
  int b = bh >> 4, h = bh & 15;
#pragma unroll
  for (int n2 = 0; n2 < 4; ++n2) {
#pragma unroll
    for (int r = 0; r < 4; ++r) {
      int q = qw + 4 * g + r;
      int hd = n2 * 16 + li;
      Z[(((size_t)b * Sn + q) * Hn + h) * HDn + hd] = accz[n2][r] / wsum[r];
    }
  }
}

// ---------------------------------------------------------------------------
extern "C" void kernel_launch(void* const* d_in, const int* in_sizes, int n_in,
                              void* d_out, int out_size, void* d_ws, size_t ws_size,
                              hipStream_t stream) {
  const float* query = (const float*)d_in[0];
  const float* key   = (const float*)d_in[1];
  const float* value = (const float*)d_in[2];
  // d_in[3] = mask (causal tril by construction; not needed)
  const float* Wq = (const float*)d_in[4];
  const float* bq = (const float*)d_in[5];
  const float* Wk = (const float*)d_in[6];
  const float* bk = (const float*)d_in[7];
  const float* Wv = (const float*)d_in[8];
  const float* bv = (const float*)d_in[9];
  const float* Wo = (const float*)d_in[10];
  const float* bo = (const float*)d_in[11];

  char* ws = (char*)d_ws;
  const size_t MB = 1ull << 20;
  unsigned short* Wqt = (unsigned short*)(ws + 0 * MB);
  unsigned short* Wkt = (unsigned short*)(ws + 2 * MB);
  unsigned short* Wvt = (unsigned short*)(ws + 4 * MB);
  unsigned short* Wot = (unsigned short*)(ws + 6 * MB);
  unsigned short* Qb  = (unsigned short*)(ws + 8 * MB);   // [b,h,s,hd] bf16
  unsigned short* Kb  = (unsigned short*)(ws + 16 * MB);
  unsigned short* Vb  = (unsigned short*)(ws + 24 * MB);
  unsigned short* Qr  = (unsigned short*)(ws + 32 * MB);
  unsigned short* Kr  = (unsigned short*)(ws + 40 * MB);
  unsigned short* Vt  = (unsigned short*)(ws + 48 * MB);  // [b,h,hd,s] bf16
  float* Zf           = (float*)(ws + 56 * MB);           // [b,s,h,hd] f32

  // 1. transpose+convert weights
  k_wtrans<<<dim3(16, 16, 4), 256, 0, stream>>>(Wq, Wk, Wv, Wo, Wqt, Wkt, Wvt, Wot);
  // 2. projections (write bf16 [b,h,s,hd])
  k_gemm<0><<<dim3(32, 8), 256, 0, stream>>>(query, Wqt, bq, Qb);
  k_gemm<0><<<dim3(32, 8), 256, 0, stream>>>(key,   Wkt, bk, Kb);
  k_gemm<0><<<dim3(32, 8), 256, 0, stream>>>(value, Wvt, bv, Vb);
  // 3. RoPE on Q,K
  k_rope<<<4096, 256, 0, stream>>>(Qb, Kb, Qr, Kr);
  // 4. V transpose
  k_vtrans<<<dim3(32, 32), 256, 0, stream>>>(Vb, Vt);
  // 5. attention
  k_attn<<<dim3(32, 32), 256, 0, stream>>>(Qr, Kr, Qb, Kb, Vt, Zf);
  // 6. output projection (f32 out)
  k_gemm<1><<<dim3(32, 8), 256, 0, stream>>>(Zf, Wot, bo, d_out);
}

// Round 2
// 280.281 us; speedup vs baseline: 1.2085x; 1.2085x over previous
//
#include <hip/hip_runtime.h>

// ---------------------------------------------------------------------------
// RoPE Multi-Headed Attention (quirky softmax(exp(qr·kr)/den) variant)
// B=2, S=2048, D=1024, H=16, HD=64
// ---------------------------------------------------------------------------

#define Bn 2
#define Sn 2048
#define Dn 1024
#define Hn 16
#define HDn 64

typedef __attribute__((ext_vector_type(8))) short bf16x8;
typedef __attribute__((ext_vector_type(8))) unsigned short u16x8;
typedef __attribute__((ext_vector_type(4))) unsigned short u16x4;
typedef __attribute__((ext_vector_type(4))) float f32x4;

#define MFMA(a, b, c) __builtin_amdgcn_mfma_f32_16x16x32_bf16(a, b, c, 0, 0, 0)

__device__ __forceinline__ unsigned short f2bf(float f) {
  unsigned int u = __builtin_bit_cast(unsigned int, f);
  u = (u + 0x7fffu + ((u >> 16) & 1u)) >> 16;
  return (unsigned short)u;
}
__device__ __forceinline__ float bf2f(unsigned short u) {
  return __builtin_bit_cast(float, (unsigned int)u << 16);
}

// ---------------------------------------------------------------------------
// 0. cos/sin table: T[s*32+i] = (cos(s*theta_i), sin(s*theta_i))
// ---------------------------------------------------------------------------
__global__ __launch_bounds__(256) void k_trig(float2* __restrict__ T) {
  int idx = blockIdx.x * 256 + threadIdx.x;  // 65536
  int s = idx >> 5, i = idx & 31;
  float theta = powf(1000.f, -(float)i / 32.f);
  float pm = (float)s * theta;
  T[idx] = make_float2(cosf(pm), sinf(pm));
}

// ---------------------------------------------------------------------------
// 1. Weight transpose+convert: W[k][n] f32 -> Wt[n][k] bf16   (4 weights)
// ---------------------------------------------------------------------------
__global__ __launch_bounds__(256) void k_wtrans(
    const float* __restrict__ W0, const float* __restrict__ W1,
    const float* __restrict__ W2, const float* __restrict__ W3,
    unsigned short* __restrict__ O0, unsigned short* __restrict__ O1,
    unsigned short* __restrict__ O2, unsigned short* __restrict__ O3) {
  __shared__ float t[64][65];
  int which = blockIdx.z;
  const float* W = (which == 0) ? W0 : (which == 1) ? W1 : (which == 2) ? W2 : W3;
  unsigned short* O = (which == 0) ? O0 : (which == 1) ? O1 : (which == 2) ? O2 : O3;
  int kb = blockIdx.x * 64, nb = blockIdx.y * 64;
  int tid = threadIdx.x;
#pragma unroll
  for (int rep = 0; rep < 16; ++rep) {
    int e = rep * 256 + tid;
    int k = e >> 6, n = e & 63;
    t[k][n] = W[(kb + k) * Dn + nb + n];
  }
  __syncthreads();
#pragma unroll
  for (int rep = 0; rep < 16; ++rep) {
    int e = rep * 256 + tid;
    int n = e >> 6, k = e & 63;
    O[(nb + n) * Dn + kb + k] = f2bf(t[k][n]);
  }
}

// ---------------------------------------------------------------------------
// 2. Fused QKV projection GEMM. grid (32, 8, 3); z picks {Q, K, V}.
//    Q/K: write base (bf16 [b,h,s,hd]) AND roped (via trig table, shfl pairs)
//    V:   write transposed Vt [b,h,hd,s] (packed 4-short stores)
// ---------------------------------------------------------------------------
__global__ __launch_bounds__(256) void k_gemm_proj(
    const float* __restrict__ Aq, const float* __restrict__ Ak, const float* __restrict__ Av,
    const unsigned short* __restrict__ Wq, const unsigned short* __restrict__ Wk,
    const unsigned short* __restrict__ Wv,
    const float* __restrict__ bqp, const float* __restrict__ bkp, const float* __restrict__ bvp,
    const float2* __restrict__ trig,
    unsigned short* __restrict__ Qb, unsigned short* __restrict__ Kb,
    unsigned short* __restrict__ Qr, unsigned short* __restrict__ Kr,
    unsigned short* __restrict__ Vt) {
  __shared__ unsigned short Al[128][72];
  __shared__ unsigned short Bl[128][72];
  const int tid = threadIdx.x;
  const int wave = tid >> 6, lane = tid & 63, g = lane >> 4, li = lane & 15;
  const int mbase = blockIdx.x * 128, nbase = blockIdx.y * 128;
  const int wm = wave >> 1, wn = wave & 1;
  const int which = blockIdx.z;
  const float* A = (which == 0) ? Aq : (which == 1) ? Ak : Av;
  const unsigned short* Wt = (which == 0) ? Wq : (which == 1) ? Wk : Wv;
  const float* bias = (which == 0) ? bqp : (which == 1) ? bkp : bvp;

  f32x4 acc[4][4];
#pragma unroll
  for (int i = 0; i < 4; ++i)
#pragma unroll
    for (int j = 0; j < 4; ++j) acc[i][j] = (f32x4){0.f, 0.f, 0.f, 0.f};

  float bv4[4];
#pragma unroll
  for (int nt = 0; nt < 4; ++nt) bv4[nt] = bias[nbase + wn * 64 + nt * 16 + li];

  const int srow = tid >> 1, scs = (tid & 1) * 32;

  for (int kb = 0; kb < Dn; kb += 64) {
    __syncthreads();
    const float* Ap = A + (size_t)(mbase + srow) * Dn + kb + scs;
#pragma unroll
    for (int i = 0; i < 4; ++i) {
      float4 v0 = *(const float4*)(Ap + i * 8);
      float4 v1 = *(const float4*)(Ap + i * 8 + 4);
      u16x8 pk;
      pk[0] = f2bf(v0.x); pk[1] = f2bf(v0.y); pk[2] = f2bf(v0.z); pk[3] = f2bf(v0.w);
      pk[4] = f2bf(v1.x); pk[5] = f2bf(v1.y); pk[6] = f2bf(v1.z); pk[7] = f2bf(v1.w);
      *(u16x8*)&Al[srow][scs + i * 8] = pk;
    }
    const unsigned short* Bp = Wt + (size_t)(nbase + srow) * Dn + kb + scs;
#pragma unroll
    for (int i = 0; i < 4; ++i)
      *(u16x8*)&Bl[srow][scs + i * 8] = *(const u16x8*)(Bp + i * 8);
    __syncthreads();

#pragma unroll
    for (int kc = 0; kc < 2; ++kc) {
      bf16x8 af[4], bfr[4];
#pragma unroll
      for (int mt = 0; mt < 4; ++mt)
        af[mt] = *(const bf16x8*)&Al[wm * 64 + mt * 16 + li][kc * 32 + g * 8];
#pragma unroll
      for (int nt = 0; nt < 4; ++nt)
        bfr[nt] = *(const bf16x8*)&Bl[wn * 64 + nt * 16 + li][kc * 32 + g * 8];
#pragma unroll
      for (int mt = 0; mt < 4; ++mt)
#pragma unroll
        for (int nt = 0; nt < 4; ++nt)
          acc[mt][nt] = MFMA(af[mt], bfr[nt], acc[mt][nt]);
    }
  }

  if (which < 2) {
    unsigned short* Ob = (which == 0) ? Qb : Kb;
    unsigned short* Or = (which == 0) ? Qr : Kr;
#pragma unroll
    for (int mt = 0; mt < 4; ++mt) {
#pragma unroll
      for (int nt = 0; nt < 4; ++nt) {
        const int n = nbase + wn * 64 + nt * 16 + li;
        const int h = n >> 6, hd = n & 63;
        const int ti = hd >> 1;
        const float sgn = (hd & 1) ? 1.f : -1.f;
#pragma unroll
        for (int r = 0; r < 4; ++r) {
          const int m = mbase + wm * 64 + mt * 16 + 4 * g + r;
          const int b = m >> 11, s = m & (Sn - 1);
          const float v = acc[mt][nt][r] + bv4[nt];
          const size_t oi = (((size_t)(b * Hn + h)) * Sn + s) * HDn + hd;
          Ob[oi] = f2bf(v);
          const float p = __shfl_xor(v, 1);
          const float2 cs = trig[(s << 5) + ti];
          Or[oi] = f2bf(fmaf(sgn * p, cs.y, v * cs.x));
        }
      }
    }
  } else {
#pragma unroll
    for (int mt = 0; mt < 4; ++mt) {
#pragma unroll
      for (int nt = 0; nt < 4; ++nt) {
        const int n = nbase + wn * 64 + nt * 16 + li;
        const int h = n >> 6, hd = n & 63;
        const int m0 = mbase + wm * 64 + mt * 16 + 4 * g;
        const int b = m0 >> 11, s0 = m0 & (Sn - 1);
        u16x4 pk;
#pragma unroll
        for (int r = 0; r < 4; ++r) pk[r] = f2bf(acc[mt][nt][r] + bv4[nt]);
        *(u16x4*)&Vt[(((size_t)(b * Hn + h)) * HDn + hd) * Sn + s0] = pk;
      }
    }
  }
}

// ---------------------------------------------------------------------------
// 3. Output GEMM: A bf16 [4096][1024] row-major, out f32 [m][n] + bias
// ---------------------------------------------------------------------------
__global__ __launch_bounds__(256) void k_gemm_out(const unsigned short* __restrict__ A,
                                                  const unsigned short* __restrict__ Wt,
                                                  const float* __restrict__ bias,
                                                  float* __restrict__ out) {
  __shared__ unsigned short Al[128][72];
  __shared__ unsigned short Bl[128][72];
  const int tid = threadIdx.x;
  const int wave = tid >> 6, lane = tid & 63, g = lane >> 4, li = lane & 15;
  const int mbase = blockIdx.x * 128, nbase = blockIdx.y * 128;
  const int wm = wave >> 1, wn = wave & 1;

  f32x4 acc[4][4];
#pragma unroll
  for (int i = 0; i < 4; ++i)
#pragma unroll
    for (int j = 0; j < 4; ++j) acc[i][j] = (f32x4){0.f, 0.f, 0.f, 0.f};

  float bv4[4];
#pragma unroll
  for (int nt = 0; nt < 4; ++nt) bv4[nt] = bias[nbase + wn * 64 + nt * 16 + li];

  const int srow = tid >> 1, scs = (tid & 1) * 32;

  for (int kb = 0; kb < Dn; kb += 64) {
    __syncthreads();
    const unsigned short* Ap = A + (size_t)(mbase + srow) * Dn + kb + scs;
    const unsigned short* Bp = Wt + (size_t)(nbase + srow) * Dn + kb + scs;
#pragma unroll
    for (int i = 0; i < 4; ++i) {
      *(u16x8*)&Al[srow][scs + i * 8] = *(const u16x8*)(Ap + i * 8);
      *(u16x8*)&Bl[srow][scs + i * 8] = *(const u16x8*)(Bp + i * 8);
    }
    __syncthreads();

#pragma unroll
    for (int kc = 0; kc < 2; ++kc) {
      bf16x8 af[4], bfr[4];
#pragma unroll
      for (int mt = 0; mt < 4; ++mt)
        af[mt] = *(const bf16x8*)&Al[wm * 64 + mt * 16 + li][kc * 32 + g * 8];
#pragma unroll
      for (int nt = 0; nt < 4; ++nt)
        bfr[nt] = *(const bf16x8*)&Bl[wn * 64 + nt * 16 + li][kc * 32 + g * 8];
#pragma unroll
      for (int mt = 0; mt < 4; ++mt)
#pragma unroll
        for (int nt = 0; nt < 4; ++nt)
          acc[mt][nt] = MFMA(af[mt], bfr[nt], acc[mt][nt]);
    }
  }

#pragma unroll
  for (int mt = 0; mt < 4; ++mt)
#pragma unroll
    for (int nt = 0; nt < 4; ++nt) {
      const int n = nbase + wn * 64 + nt * 16 + li;
#pragma unroll
      for (int r = 0; r < 4; ++r) {
        const int m = mbase + wm * 64 + mt * 16 + 4 * g + r;
        out[(size_t)m * Dn + n] = acc[mt][nt][r] + bv4[nt];
      }
    }
}

// ---------------------------------------------------------------------------
// 4. Attention. Block = 4 waves x 16 q-rows; grid (S/64, B*H).
//    Double-buffered LDS (one barrier/iter), XOR-swizzled tiles, causal
//    specialization. Output Z as bf16 [m][H*HD] row-major.
// ---------------------------------------------------------------------------
__global__ __launch_bounds__(256) void k_attn(
    const unsigned short* __restrict__ Qr, const unsigned short* __restrict__ Kr,
    const unsigned short* __restrict__ Qb, const unsigned short* __restrict__ Kb,
    const unsigned short* __restrict__ Vt, unsigned short* __restrict__ Zb) {
  __shared__ unsigned short KT[2][2][64 * 64];  // [buf][tensor][row*64 + swz col]
  __shared__ unsigned short Pl[4][16 * 64];     // per-wave P, swizzled

  const int tid = threadIdx.x;
  const int wave = tid >> 6, lane = tid & 63, g = lane >> 4, li = lane & 15;
  const int qt = blockIdx.x, bh = blockIdx.y;
  const int qbase = qt * 64, qw = qbase + wave * 16;
  const size_t kvbase = (size_t)bh * (Sn * HDn);

  // Q fragments (A operand)
  bf16x8 qrf[2], qbf[2];
#pragma unroll
  for (int kc = 0; kc < 2; ++kc) {
    const size_t a = kvbase + (size_t)(qw + li) * HDn + kc * 32 + g * 8;
    qrf[kc] = *(const bf16x8*)(Qr + a);
    qbf[kc] = *(const bf16x8*)(Qb + a);
  }

  // staging geometry: wave stages tensor (wave>>1), rows (wave&1)*32..+31
  const int stens = wave >> 1;
  const int srbase = (wave & 1) * 32;
  const int lrow = (lane >> 3) & 7, lchunk = lane & 7;
  int woff[4];
#pragma unroll
  for (int i = 0; i < 4; ++i)
    woff[i] = (srbase + i * 8 + lrow) * 64 + ((lchunk ^ lrow) * 8);

  const unsigned short* sK0 = Kr + kvbase + (size_t)(srbase + lrow) * HDn + lchunk * 8;
  const unsigned short* sK1 = Kb + kvbase + (size_t)(srbase + lrow) * HDn + lchunk * 8;
  const unsigned short* sV1 = Vt + kvbase + (size_t)(srbase + lrow) * Sn + lchunk * 8;
  const unsigned short* sA = stens ? sK1 : sK0;

  unsigned short* KTf = &KT[0][0][0];
  unsigned short* myP = &Pl[wave][0];
  const int xs = li & 7;

  // ------------------- PASS A -------------------
  float densum[4] = {0.f, 0.f, 0.f, 0.f};
  float mx[4] = {-1e30f, -1e30f, -1e30f, -1e30f};

#pragma unroll
  for (int i = 0; i < 4; ++i)
    *(u16x8*)(KTf + stens * 4096 + woff[i]) = *(const u16x8*)(sA + i * (8 * HDn));
  __syncthreads();

  int cur = 0;
  for (int t = 0; t < Sn / 64; ++t) {
    const int kb = t * 64;
    u16x8 stg[4];
    const bool more = (t < Sn / 64 - 1);
    if (more) {
#pragma unroll
      for (int i = 0; i < 4; ++i)
        stg[i] = *(const u16x8*)(sA + (size_t)(kb + 64) * HDn + i * (8 * HDn));
    }
    const unsigned short* T0 = KTf + (cur * 2 + 0) * 4096;
    const unsigned short* T1 = KTf + (cur * 2 + 1) * 4096;
#pragma unroll
    for (int nt = 0; nt < 4; ++nt) {
      const int ktile = kb + nt * 16;
      const int rb = (nt * 16 + li) * 64;
      f32x4 acc2 = (f32x4){0.f, 0.f, 0.f, 0.f};
#pragma unroll
      for (int kc = 0; kc < 2; ++kc) {
        const bf16x8 kbf = *(const bf16x8*)(T1 + rb + (((kc * 4 + g) ^ xs) * 8));
        acc2 = MFMA(qbf[kc], kbf, acc2);
      }
#pragma unroll
      for (int r = 0; r < 4; ++r) densum[r] += __expf(acc2[r] * 0.125f);
      if (ktile <= qw + 15) {  // tile has causal-valid columns for this wave
        f32x4 acc = (f32x4){0.f, 0.f, 0.f, 0.f};
#pragma unroll
        for (int kc = 0; kc < 2; ++kc) {
          const bf16x8 krf = *(const bf16x8*)(T0 + rb + (((kc * 4 + g) ^ xs) * 8));
          acc = MFMA(qrf[kc], krf, acc);
        }
        if (ktile + 15 <= qw) {
#pragma unroll
          for (int r = 0; r < 4; ++r) mx[r] = fmaxf(mx[r], acc[r] * 0.125f);
        } else {
          const int kg = ktile + li;
#pragma unroll
          for (int r = 0; r < 4; ++r)
            if (kg <= qw + 4 * g + r) mx[r] = fmaxf(mx[r], acc[r] * 0.125f);
        }
      }
    }
    if (more) {
      unsigned short* W = KTf + ((cur ^ 1) * 2 + stens) * 4096;
#pragma unroll
      for (int i = 0; i < 4; ++i) *(u16x8*)(W + woff[i]) = stg[i];
    }
    __syncthreads();
    cur ^= 1;
  }

  float Lr[4], am[4];
#pragma unroll
  for (int r = 0; r < 4; ++r) {
    float d = densum[r], m = mx[r];
#pragma unroll
    for (int off = 1; off < 16; off <<= 1) {
      d += __shfl_xor(d, off);
      m = fmaxf(m, __shfl_xor(m, off));
    }
    Lr[r] = __logf(d);
    am[r] = __expf(m - Lr[r]);
  }

  // ------------------- PASS B -------------------
  f32x4 accz[4];
#pragma unroll
  for (int i = 0; i < 4; ++i) accz[i] = (f32x4){0.f, 0.f, 0.f, 0.f};
  float wsum[4] = {0.f, 0.f, 0.f, 0.f};
  const int NTB = qt + 1;
  const unsigned short* sB = stens ? sV1 : sK0;
  const size_t strTile = stens ? (size_t)64 : (size_t)(64 * HDn);
  const size_t strI = stens ? (size_t)(8 * Sn) : (size_t)(8 * HDn);

#pragma unroll
  for (int i = 0; i < 4; ++i)
    *(u16x8*)(KTf + stens * 4096 + woff[i]) = *(const u16x8*)(sB + i * strI);
  __syncthreads();

  cur = 0;
  for (int t = 0; t < NTB; ++t) {
    const int kb = t * 64;
    u16x8 stg[4];
    const bool more = (t < NTB - 1);
    if (more) {
#pragma unroll
      for (int i = 0; i < 4; ++i)
        stg[i] = *(const u16x8*)(sB + (size_t)(t + 1) * strTile + i * strI);
    }
    if (kb <= qw + 15) {  // wave-level causal skip
      const unsigned short* T0 = KTf + (cur * 2 + 0) * 4096;
      const unsigned short* T1 = KTf + (cur * 2 + 1) * 4096;
#pragma unroll
      for (int nt = 0; nt < 4; ++nt) {
        const int ktile = kb + nt * 16;
        if (ktile <= qw + 15) {
          const int rb = (nt * 16 + li) * 64;
          f32x4 acc = (f32x4){0.f, 0.f, 0.f, 0.f};
#pragma unroll
          for (int kc = 0; kc < 2; ++kc) {
            const bf16x8 krf = *(const bf16x8*)(T0 + rb + (((kc * 4 + g) ^ xs) * 8));
            acc = MFMA(qrf[kc], krf, acc);
          }
          const bool full = (ktile + 15 <= qw);
#pragma unroll
          for (int r = 0; r < 4; ++r) {
            const int prow = 4 * g + r;
            const float a = __expf(fmaf(acc[r], 0.125f, -Lr[r]));
            float w = __expf(a - am[r]);
            if (!full && (ktile + li > qw + prow)) w = 0.f;
            wsum[r] += w;
            myP[prow * 64 + (((nt * 2 + (li >> 3)) ^ (prow & 7)) * 8) + (li & 7)] = f2bf(w);
          }
        } else {
#pragma unroll
          for (int r = 0; r < 4; ++r) {
            const int prow = 4 * g + r;
            myP[prow * 64 + (((nt * 2 + (li >> 3)) ^ (prow & 7)) * 8) + (li & 7)] = 0;
          }
        }
      }
      // PV
#pragma unroll
      for (int kc = 0; kc < 2; ++kc) {
        const bf16x8 pa = *(const bf16x8*)(myP + li * 64 + (((kc * 4 + g) ^ xs) * 8));
#pragma unroll
        for (int n2 = 0; n2 < 4; ++n2) {
          const bf16x8 vb = *(const bf16x8*)(T1 + (n2 * 16 + li) * 64 + (((kc * 4 + g) ^ xs) * 8));
          accz[n2] = MFMA(pa, vb, accz[n2]);
        }
      }
    }
    if (more) {
      unsigned short* W = KTf + ((cur ^ 1) * 2 + stens) * 4096;
#pragma unroll
      for (int i = 0; i < 4; ++i) *(u16x8*)(W + woff[i]) = stg[i];
    }
    __syncthreads();
    cur ^= 1;
  }

  // normalize + write bf16 [m][H*HD]
#pragma unroll
  for (int r = 0; r < 4; ++r) {
    float w = wsum[r];
#pragma unroll
    for (int off = 1; off < 16; off <<= 1) w += __shfl_xor(w, off);
    wsum[r] = w;
  }
  const int b = bh >> 4, h = bh & 15;
#pragma unroll
  for (int n2 = 0; n2 < 4; ++n2) {
#pragma unroll
    for (int r = 0; r < 4; ++r) {
      const int q = qw + 4 * g + r;
      const int hd = n2 * 16 + li;
      Zb[((size_t)(b * Sn + q)) * Dn + h * HDn + hd] = f2bf(accz[n2][r] / wsum[r]);
    }
  }
}

// ---------------------------------------------------------------------------
extern "C" void kernel_launch(void* const* d_in, const int* in_sizes, int n_in,
                              void* d_out, int out_size, void* d_ws, size_t ws_size,
                              hipStream_t stream) {
  const float* query = (const float*)d_in[0];
  const float* key   = (const float*)d_in[1];
  const float* value = (const float*)d_in[2];
  const float* Wq = (const float*)d_in[4];
  const float* bq = (const float*)d_in[5];
  const float* Wk = (const float*)d_in[6];
  const float* bk = (const float*)d_in[7];
  const float* Wv = (const float*)d_in[8];
  const float* bv = (const float*)d_in[9];
  const float* Wo = (const float*)d_in[10];
  const float* bo = (const float*)d_in[11];

  char* ws = (char*)d_ws;
  const size_t MB = 1ull << 20;
  unsigned short* Wqt = (unsigned short*)(ws + 0 * MB);
  unsigned short* Wkt = (unsigned short*)(ws + 2 * MB);
  unsigned short* Wvt = (unsigned short*)(ws + 4 * MB);
  unsigned short* Wot = (unsigned short*)(ws + 6 * MB);
  float2* trig        = (float2*)(ws + 8 * MB);           // 512 KB
  unsigned short* Qb  = (unsigned short*)(ws + 10 * MB);  // [b,h,s,hd] bf16
  unsigned short* Kb  = (unsigned short*)(ws + 18 * MB);
  unsigned short* Qr  = (unsigned short*)(ws + 26 * MB);
  unsigned short* Kr  = (unsigned short*)(ws + 34 * MB);
  unsigned short* Vt  = (unsigned short*)(ws + 42 * MB);  // [b,h,hd,s] bf16
  unsigned short* Zb  = (unsigned short*)(ws + 50 * MB);  // [m][1024] bf16

  k_trig<<<256, 256, 0, stream>>>(trig);
  k_wtrans<<<dim3(16, 16, 4), 256, 0, stream>>>(Wq, Wk, Wv, Wo, Wqt, Wkt, Wvt, Wot);
  k_gemm_proj<<<dim3(32, 8, 3), 256, 0, stream>>>(query, key, value, Wqt, Wkt, Wvt,
                                                  bq, bk, bv, trig, Qb, Kb, Qr, Kr, Vt);
  k_attn<<<dim3(32, 32), 256, 0, stream>>>(Qr, Kr, Qb, Kb, Vt, Zb);
  k_gemm_out<<<dim3(32, 8), 256, 0, stream>>>(Zb, Wot, bo, (float*)d_out);
}

// Round 3
// 194.191 us; speedup vs baseline: 1.7443x; 1.4433x over previous
//
#include <hip/hip_runtime.h>

// ---------------------------------------------------------------------------
// RoPE Multi-Headed Attention (quirky softmax(exp(qr·kr)/den) variant)
// B=2, S=2048, D=1024, H=16, HD=64
// ---------------------------------------------------------------------------

#define Bn 2
#define Sn 2048
#define Dn 1024
#define Hn 16
#define HDn 64

typedef __attribute__((ext_vector_type(8))) short bf16x8;
typedef __attribute__((ext_vector_type(8))) unsigned short u16x8;
typedef __attribute__((ext_vector_type(4))) unsigned short u16x4;
typedef __attribute__((ext_vector_type(4))) float f32x4;

#define MFMA(a, b, c) __builtin_amdgcn_mfma_f32_16x16x32_bf16(a, b, c, 0, 0, 0)
#define Z4 ((f32x4){0.f, 0.f, 0.f, 0.f})

__device__ __forceinline__ unsigned short f2bf(float f) {
  unsigned int u = __builtin_bit_cast(unsigned int, f);
  u = (u + 0x7fffu + ((u >> 16) & 1u)) >> 16;
  return (unsigned short)u;
}

// async global->LDS, 16B per lane; dst is wave-uniform base (lane writes +lane*16B)
__device__ __forceinline__ void gll16(const unsigned short* g, unsigned short* l) {
  __builtin_amdgcn_global_load_lds((const __attribute__((address_space(1))) void*)g,
                                   (__attribute__((address_space(3))) void*)l, 16, 0, 0);
}

// swizzled fragment read: LDS slot c of row r holds source chunk c^(r&7)
#define FR(T, row, x) (*(const bf16x8*)&(T)[(row) * 64 + (((x) ^ ((row) & 7)) * 8)])

// ---------------------------------------------------------------------------
// 0. cos/sin table: T[s*32+i] = (cos(s*theta_i), sin(s*theta_i))
// ---------------------------------------------------------------------------
__global__ __launch_bounds__(256) void k_trig(float2* __restrict__ T) {
  int idx = blockIdx.x * 256 + threadIdx.x;  // 65536
  int s = idx >> 5, i = idx & 31;
  float theta = powf(1000.f, -(float)i / 32.f);
  float pm = (float)s * theta;
  T[idx] = make_float2(cosf(pm), sinf(pm));
}

// ---------------------------------------------------------------------------
// 1. Weight transpose+convert: W[k][n] f32 -> Wt[n][k] bf16   (4 weights)
// ---------------------------------------------------------------------------
__global__ __launch_bounds__(256) void k_wtrans(
    const float* __restrict__ W0, const float* __restrict__ W1,
    const float* __restrict__ W2, const float* __restrict__ W3,
    unsigned short* __restrict__ O0, unsigned short* __restrict__ O1,
    unsigned short* __restrict__ O2, unsigned short* __restrict__ O3) {
  __shared__ float t[64][65];
  int which = blockIdx.z;
  const float* W = (which == 0) ? W0 : (which == 1) ? W1 : (which == 2) ? W2 : W3;
  unsigned short* O = (which == 0) ? O0 : (which == 1) ? O1 : (which == 2) ? O2 : O3;
  int kb = blockIdx.x * 64, nb = blockIdx.y * 64;
  int tid = threadIdx.x;
#pragma unroll
  for (int rep = 0; rep < 16; ++rep) {
    int e = rep * 256 + tid;
    int k = e >> 6, n = e & 63;
    t[k][n] = W[(kb + k) * Dn + nb + n];
  }
  __syncthreads();
#pragma unroll
  for (int rep = 0; rep < 16; ++rep) {
    int e = rep * 256 + tid;
    int n = e >> 6, k = e & 63;
    O[(nb + n) * Dn + kb + k] = f2bf(t[k][n]);
  }
}

// ---------------------------------------------------------------------------
// 2. Activation convert f32 -> bf16. grid (2048, 3); y picks tensor.
// ---------------------------------------------------------------------------
__global__ __launch_bounds__(256) void k_cvt(
    const float* __restrict__ q, const float* __restrict__ k, const float* __restrict__ v,
    unsigned short* __restrict__ oq, unsigned short* __restrict__ ok,
    unsigned short* __restrict__ ov) {
  int z = blockIdx.y;
  const float* s = (z == 0) ? q : (z == 1) ? k : v;
  unsigned short* d = (z == 0) ? oq : (z == 1) ? ok : ov;
  size_t idx = ((size_t)blockIdx.x * 256 + threadIdx.x) * 8;
  float4 a = *(const float4*)(s + idx);
  float4 b = *(const float4*)(s + idx + 4);
  u16x8 pk;
  pk[0] = f2bf(a.x); pk[1] = f2bf(a.y); pk[2] = f2bf(a.z); pk[3] = f2bf(a.w);
  pk[4] = f2bf(b.x); pk[5] = f2bf(b.y); pk[6] = f2bf(b.z); pk[7] = f2bf(b.w);
  *(u16x8*)(d + idx) = pk;
}

// ---------------------------------------------------------------------------
// 3. Fused QKV projection GEMM (gll-staged). grid (32, 8, 3); z = {Q,K,V}.
//    Q: prescaled by 0.125; Q/K write base + roped; V writes Vt [b,h,hd,s].
// ---------------------------------------------------------------------------
__global__ __launch_bounds__(256) void k_gemm_proj(
    const unsigned short* __restrict__ Qa, const unsigned short* __restrict__ Ka,
    const unsigned short* __restrict__ Va,
    const unsigned short* __restrict__ Wq, const unsigned short* __restrict__ Wk,
    const unsigned short* __restrict__ Wv,
    const float* __restrict__ bqp, const float* __restrict__ bkp, const float* __restrict__ bvp,
    const float2* __restrict__ trig,
    unsigned short* __restrict__ Qb, unsigned short* __restrict__ Kb,
    unsigned short* __restrict__ Qr, unsigned short* __restrict__ Kr,
    unsigned short* __restrict__ Vt) {
  __shared__ unsigned short Al[128 * 64];
  __shared__ unsigned short Bl[128 * 64];
  const int tid = threadIdx.x;
  const int wave = tid >> 6, lane = tid & 63, g = lane >> 4, li = lane & 15;
  const int mbase = blockIdx.x * 128, nbase = blockIdx.y * 128;
  const int wm = wave >> 1, wn = wave & 1;
  const int which = blockIdx.z;
  const unsigned short* A = (which == 0) ? Qa : (which == 1) ? Ka : Va;
  const unsigned short* Wt = (which == 0) ? Wq : (which == 1) ? Wk : Wv;
  const float* bias = (which == 0) ? bqp : (which == 1) ? bkp : bvp;

  f32x4 acc[4][4];
#pragma unroll
  for (int i = 0; i < 4; ++i)
#pragma unroll
    for (int j = 0; j < 4; ++j) acc[i][j] = Z4;

  float bv4[4];
#pragma unroll
  for (int nt = 0; nt < 4; ++nt) bv4[nt] = bias[nbase + wn * 64 + nt * 16 + li];

  const int lr8 = lane >> 3, lc = lane & 7;
  const int xc8 = (lc ^ lr8) * 8;
  const unsigned short* srcA = A + (size_t)(mbase + wave * 32 + lr8) * Dn + xc8;
  const unsigned short* srcB = Wt + (size_t)(nbase + wave * 32 + lr8) * Dn + xc8;

  for (int kb = 0; kb < Dn; kb += 64) {
    __syncthreads();
#pragma unroll
    for (int i = 0; i < 4; ++i) {
      gll16(srcA + kb + (size_t)i * (8 * Dn), &Al[(wave * 32 + i * 8) * 64]);
      gll16(srcB + kb + (size_t)i * (8 * Dn), &Bl[(wave * 32 + i * 8) * 64]);
    }
    __syncthreads();
#pragma unroll
    for (int kc = 0; kc < 2; ++kc) {
      bf16x8 af[4], bfr[4];
#pragma unroll
      for (int mt = 0; mt < 4; ++mt) af[mt] = FR(Al, wm * 64 + mt * 16 + li, kc * 4 + g);
#pragma unroll
      for (int nt = 0; nt < 4; ++nt) bfr[nt] = FR(Bl, wn * 64 + nt * 16 + li, kc * 4 + g);
#pragma unroll
      for (int mt = 0; mt < 4; ++mt)
#pragma unroll
        for (int nt = 0; nt < 4; ++nt)
          acc[mt][nt] = MFMA(af[mt], bfr[nt], acc[mt][nt]);
    }
  }

  if (which < 2) {
    unsigned short* Ob = (which == 0) ? Qb : Kb;
    unsigned short* Or = (which == 0) ? Qr : Kr;
    const float presc = (which == 0) ? 0.125f : 1.f;  // fold 1/sqrt(HD) into Q (exact in bf16)
#pragma unroll
    for (int mt = 0; mt < 4; ++mt) {
#pragma unroll
      for (int nt = 0; nt < 4; ++nt) {
        const int n = nbase + wn * 64 + nt * 16 + li;
        const int h = n >> 6, hd = n & 63;
        const int ti = hd >> 1;
        const float sgn = (hd & 1) ? 1.f : -1.f;
#pragma unroll
        for (int r = 0; r < 4; ++r) {
          const int m = mbase + wm * 64 + mt * 16 + 4 * g + r;
          const int b = m >> 11, s = m & (Sn - 1);
          const float v = (acc[mt][nt][r] + bv4[nt]) * presc;
          const size_t oi = (((size_t)(b * Hn + h)) * Sn + s) * HDn + hd;
          Ob[oi] = f2bf(v);
          const float p = __shfl_xor(v, 1);
          const float2 cs = trig[(s << 5) + ti];
          Or[oi] = f2bf(fmaf(sgn * p, cs.y, v * cs.x));
        }
      }
    }
  } else {
#pragma unroll
    for (int mt = 0; mt < 4; ++mt) {
#pragma unroll
      for (int nt = 0; nt < 4; ++nt) {
        const int n = nbase + wn * 64 + nt * 16 + li;
        const int h = n >> 6, hd = n & 63;
        const int m0 = mbase + wm * 64 + mt * 16 + 4 * g;
        const int b = m0 >> 11, s0 = m0 & (Sn - 1);
        u16x4 pk;
#pragma unroll
        for (int r = 0; r < 4; ++r) pk[r] = f2bf(acc[mt][nt][r] + bv4[nt]);
        *(u16x4*)&Vt[(((size_t)(b * Hn + h)) * HDn + hd) * Sn + s0] = pk;
      }
    }
  }
}

// ---------------------------------------------------------------------------
// 4. Output GEMM 64x128 tile (gll-staged): A bf16 [4096][1024], out f32 + bias
//    grid (64, 8) = 512 blocks (2/CU). Waves 2x2, wave tile 32x64.
// ---------------------------------------------------------------------------
__global__ __launch_bounds__(256) void k_gemm_out(const unsigned short* __restrict__ A,
                                                  const unsigned short* __restrict__ Wt,
                                                  const float* __restrict__ bias,
                                                  float* __restrict__ out) {
  __shared__ unsigned short Al[64 * 64];
  __shared__ unsigned short Bl[128 * 64];
  const int tid = threadIdx.x;
  const int wave = tid >> 6, lane = tid & 63, g = lane >> 4, li = lane & 15;
  const int mbase = blockIdx.x * 64, nbase = blockIdx.y * 128;
  const int wm = wave >> 1, wn = wave & 1;

  f32x4 acc[2][4];
#pragma unroll
  for (int i = 0; i < 2; ++i)
#pragma unroll
    for (int j = 0; j < 4; ++j) acc[i][j] = Z4;

  float bv4[4];
#pragma unroll
  for (int nt = 0; nt < 4; ++nt) bv4[nt] = bias[nbase + wn * 64 + nt * 16 + li];

  const int lr8 = lane >> 3, lc = lane & 7;
  const int xc8 = (lc ^ lr8) * 8;
  const unsigned short* srcA = A + (size_t)(mbase + wave * 16 + lr8) * Dn + xc8;
  const unsigned short* srcB = Wt + (size_t)(nbase + wave * 32 + lr8) * Dn + xc8;

  for (int kb = 0; kb < Dn; kb += 64) {
    __syncthreads();
#pragma unroll
    for (int i = 0; i < 2; ++i)
      gll16(srcA + kb + (size_t)i * (8 * Dn), &Al[(wave * 16 + i * 8) * 64]);
#pragma unroll
    for (int i = 0; i < 4; ++i)
      gll16(srcB + kb + (size_t)i * (8 * Dn), &Bl[(wave * 32 + i * 8) * 64]);
    __syncthreads();
#pragma unroll
    for (int kc = 0; kc < 2; ++kc) {
      bf16x8 af[2], bfr[4];
#pragma unroll
      for (int mt = 0; mt < 2; ++mt) af[mt] = FR(Al, wm * 32 + mt * 16 + li, kc * 4 + g);
#pragma unroll
      for (int nt = 0; nt < 4; ++nt) bfr[nt] = FR(Bl, wn * 64 + nt * 16 + li, kc * 4 + g);
#pragma unroll
      for (int mt = 0; mt < 2; ++mt)
#pragma unroll
        for (int nt = 0; nt < 4; ++nt)
          acc[mt][nt] = MFMA(af[mt], bfr[nt], acc[mt][nt]);
    }
  }

#pragma unroll
  for (int mt = 0; mt < 2; ++mt)
#pragma unroll
    for (int nt = 0; nt < 4; ++nt) {
      const int n = nbase + wn * 64 + nt * 16 + li;
#pragma unroll
      for (int r = 0; r < 4; ++r) {
        const int m = mbase + wm * 32 + mt * 16 + 4 * g + r;
        out[(size_t)m * Dn + n] = acc[mt][nt][r] + bv4[nt];
      }
    }
}

// ---------------------------------------------------------------------------
// 5. Attention, folded. grid (bh=32, f=16). Block handles q-tiles f and 31-f.
//    gll-staged double-buffered K/V tiles, one barrier/tile.
// ---------------------------------------------------------------------------
__global__ __launch_bounds__(256) void k_attn(
    const unsigned short* __restrict__ Qr, const unsigned short* __restrict__ Kr,
    const unsigned short* __restrict__ Qb, const unsigned short* __restrict__ Kb,
    const unsigned short* __restrict__ Vt, unsigned short* __restrict__ Zb) {
  __shared__ unsigned short KT[2][2][64 * 64];  // [buf][tensor] 32KB
  __shared__ unsigned short Pl[4][2][16 * 64];  // [wave][half]   16KB

  const int tid = threadIdx.x;
  const int wave = tid >> 6, lane = tid & 63, g = lane >> 4, li = lane & 15;
  const int bh = blockIdx.x, f = blockIdx.y;
  const int qtL = f, qtH = 31 - f;
  const int qwL = qtL * 64 + wave * 16, qwH = qtH * 64 + wave * 16;
  const size_t kvbase = (size_t)bh * (Sn * HDn);

  // Q fragments (Q prescaled by 0.125 at projection)
  bf16x8 qrfL[2], qbfL[2], qrfH[2], qbfH[2];
#pragma unroll
  for (int kc = 0; kc < 2; ++kc) {
    const size_t aL = kvbase + (size_t)(qwL + li) * HDn + kc * 32 + g * 8;
    const size_t aH = kvbase + (size_t)(qwH + li) * HDn + kc * 32 + g * 8;
    qrfL[kc] = *(const bf16x8*)(Qr + aL);
    qbfL[kc] = *(const bf16x8*)(Qb + aL);
    qrfH[kc] = *(const bf16x8*)(Qr + aH);
    qbfH[kc] = *(const bf16x8*)(Qb + aH);
  }

  // gll staging geometry: wave stages tensor tw, rows rb..rb+31 (4 instrs)
  const int tw = wave >> 1;
  const int rb = (wave & 1) * 32;
  const int lr8 = lane >> 3, lc = lane & 7;
  const int xc8 = (lc ^ lr8) * 8;  // swizzled chunk (source side)

  const unsigned short* srcKA = (tw ? Kb : Kr) + kvbase + (size_t)(rb + lr8) * HDn + xc8;
  const unsigned short* srcKB = tw ? (Vt + kvbase + (size_t)(rb + lr8) * Sn + xc8) : srcKA;
  const size_t strB = tw ? (size_t)(8 * Sn) : (size_t)(8 * HDn);

  unsigned short* myPL = &Pl[wave][0][0];
  unsigned short* myPH = &Pl[wave][1][0];

#define STAGE_A(kb_, buf_)                                                   \
  do {                                                                       \
    unsigned short* d_ = &KT[buf_][tw][rb * 64];                             \
    const unsigned short* s_ = srcKA + (size_t)(kb_) * HDn;                  \
    gll16(s_, d_);                                                           \
    gll16(s_ + 8 * HDn, d_ + 8 * 64);                                        \
    gll16(s_ + 16 * HDn, d_ + 16 * 64);                                      \
    gll16(s_ + 24 * HDn, d_ + 24 * 64);                                      \
  } while (0)

#define STAGE_B(kb_, buf_)                                                   \
  do {                                                                       \
    unsigned short* d_ = &KT[buf_][tw][rb * 64];                             \
    const unsigned short* s_ = srcKB + (tw ? (size_t)(kb_) : (size_t)(kb_)*HDn); \
    gll16(s_, d_);                                                           \
    gll16(s_ + strB, d_ + 8 * 64);                                           \
    gll16(s_ + 2 * strB, d_ + 16 * 64);                                      \
    gll16(s_ + 3 * strB, d_ + 24 * 64);                                      \
  } while (0)

  // ------------------- PASS A: den (all k) + causal rope max -------------------
  float densumL[4] = {0.f, 0.f, 0.f, 0.f}, densumH[4] = {0.f, 0.f, 0.f, 0.f};
  float mxL[4] = {-1e30f, -1e30f, -1e30f, -1e30f}, mxH[4] = {-1e30f, -1e30f, -1e30f, -1e30f};

  STAGE_A(0, 0);
  __syncthreads();
  int cur = 0;
  for (int t = 0; t < Sn / 64; ++t) {
    if (t + 1 < Sn / 64) STAGE_A((t + 1) * 64, cur ^ 1);
    const unsigned short* T0 = &KT[cur][0][0];  // Kr
    const unsigned short* T1 = &KT[cur][1][0];  // Kb
#pragma unroll
    for (int nt = 0; nt < 4; ++nt) {
      const int ktile = t * 64 + nt * 16;
      const int krow = nt * 16 + li;
      const bf16x8 kbf0 = FR(T1, krow, g), kbf1 = FR(T1, krow, 4 + g);
      f32x4 a2L = Z4, a2H = Z4;
      a2L = MFMA(qbfL[0], kbf0, a2L);
      a2L = MFMA(qbfL[1], kbf1, a2L);
      a2H = MFMA(qbfH[0], kbf0, a2H);
      a2H = MFMA(qbfH[1], kbf1, a2H);
#pragma unroll
      for (int r = 0; r < 4; ++r) {
        densumL[r] += __expf(a2L[r]);
        densumH[r] += __expf(a2H[r]);
      }
      if (ktile <= qwH + 15) {
        const bf16x8 krf0 = FR(T0, krow, g), krf1 = FR(T0, krow, 4 + g);
        f32x4 sH = Z4;
        sH = MFMA(qrfH[0], krf0, sH);
        sH = MFMA(qrfH[1], krf1, sH);
        if (ktile + 15 <= qwH) {
#pragma unroll
          for (int r = 0; r < 4; ++r) mxH[r] = fmaxf(mxH[r], sH[r]);
        } else {
#pragma unroll
          for (int r = 0; r < 4; ++r)
            if (ktile + li <= qwH + 4 * g + r) mxH[r] = fmaxf(mxH[r], sH[r]);
        }
        if (ktile <= qwL + 15) {
          f32x4 sL = Z4;
          sL = MFMA(qrfL[0], krf0, sL);
          sL = MFMA(qrfL[1], krf1, sL);
          if (ktile + 15 <= qwL) {
#pragma unroll
            for (int r = 0; r < 4; ++r) mxL[r] = fmaxf(mxL[r], sL[r]);
          } else {
#pragma unroll
            for (int r = 0; r < 4; ++r)
              if (ktile + li <= qwL + 4 * g + r) mxL[r] = fmaxf(mxL[r], sL[r]);
          }
        }
      }
    }
    __syncthreads();
    cur ^= 1;
  }

  float LrL[4], amL[4], LrH[4], amH[4];
#pragma unroll
  for (int r = 0; r < 4; ++r) {
    float dL = densumL[r], mL = mxL[r], dH = densumH[r], mH = mxH[r];
#pragma unroll
    for (int off = 1; off < 16; off <<= 1) {
      dL += __shfl_xor(dL, off);
      mL = fmaxf(mL, __shfl_xor(mL, off));
      dH += __shfl_xor(dH, off);
      mH = fmaxf(mH, __shfl_xor(mH, off));
    }
    LrL[r] = __logf(dL);
    amL[r] = __expf(mL - LrL[r]);
    LrH[r] = __logf(dH);
    amH[r] = __expf(mH - LrH[r]);
  }

  // ------------------- PASS B: P = exp(a - am), Z = P.V -------------------
  f32x4 acczL[4], acczH[4];
#pragma unroll
  for (int i = 0; i < 4; ++i) {
    acczL[i] = Z4;
    acczH[i] = Z4;
  }
  float wsumL[4] = {0.f, 0.f, 0.f, 0.f}, wsumH[4] = {0.f, 0.f, 0.f, 0.f};
  const int NTB = qtH + 1;

  STAGE_B(0, 0);
  __syncthreads();
  cur = 0;
  for (int t = 0; t < NTB; ++t) {
    if (t + 1 < NTB) STAGE_B((t + 1) * 64, cur ^ 1);
    const unsigned short* T0 = &KT[cur][0][0];  // Kr
    const unsigned short* TV = &KT[cur][1][0];  // V [hd][k]
    const bool loAct = (t <= qtL);
#pragma unroll
    for (int nt = 0; nt < 4; ++nt) {
      const int ktile = t * 64 + nt * 16;
      const int krow = nt * 16 + li;
      const bf16x8 krf0 = FR(T0, krow, g), krf1 = FR(T0, krow, 4 + g);
      // hi half
      if (ktile <= qwH + 15) {
        f32x4 sH = Z4;
        sH = MFMA(qrfH[0], krf0, sH);
        sH = MFMA(qrfH[1], krf1, sH);
        const bool fullH = (ktile + 15 <= qwH);
#pragma unroll
        for (int r = 0; r < 4; ++r) {
          const int prow = 4 * g + r;
          const float a = __expf(sH[r] - LrH[r]);
          float w = __expf(a - amH[r]);
          if (!fullH && (ktile + li > qwH + prow)) w = 0.f;
          wsumH[r] += w;
          myPH[prow * 64 + (((nt * 2 + (li >> 3)) ^ (prow & 7)) * 8) + (li & 7)] = f2bf(w);
        }
      } else {
#pragma unroll
        for (int r = 0; r < 4; ++r) {
          const int prow = 4 * g + r;
          myPH[prow * 64 + (((nt * 2 + (li >> 3)) ^ (prow & 7)) * 8) + (li & 7)] = 0;
        }
      }
      // lo half
      if (loAct) {
        if (ktile <= qwL + 15) {
          f32x4 sL = Z4;
          sL = MFMA(qrfL[0], krf0, sL);
          sL = MFMA(qrfL[1], krf1, sL);
          const bool fullL = (ktile + 15 <= qwL);
#pragma unroll
          for (int r = 0; r < 4; ++r) {
            const int prow = 4 * g + r;
            const float a = __expf(sL[r] - LrL[r]);
            float w = __expf(a - amL[r]);
            if (!fullL && (ktile + li > qwL + prow)) w = 0.f;
            wsumL[r] += w;
            myPL[prow * 64 + (((nt * 2 + (li >> 3)) ^ (prow & 7)) * 8) + (li & 7)] = f2bf(w);
          }
        } else {
#pragma unroll
          for (int r = 0; r < 4; ++r) {
            const int prow = 4 * g + r;
            myPL[prow * 64 + (((nt * 2 + (li >> 3)) ^ (prow & 7)) * 8) + (li & 7)] = 0;
          }
        }
      }
    }
    // PV (V frags shared by both halves)
#pragma unroll
    for (int kc = 0; kc < 2; ++kc) {
      const bf16x8 paH = FR(myPH, li, kc * 4 + g);
      bf16x8 paL;
      if (loAct) paL = FR(myPL, li, kc * 4 + g);
#pragma unroll
      for (int n2 = 0; n2 < 4; ++n2) {
        const bf16x8 vb = FR(TV, n2 * 16 + li, kc * 4 + g);
        acczH[n2] = MFMA(paH, vb, acczH[n2]);
        if (loAct) acczL[n2] = MFMA(paL, vb, acczL[n2]);
      }
    }
    __syncthreads();
    cur ^= 1;
  }

  // normalize + write bf16 [b*S+q][H*HD]
#pragma unroll
  for (int r = 0; r < 4; ++r) {
    float wL = wsumL[r], wH = wsumH[r];
#pragma unroll
    for (int off = 1; off < 16; off <<= 1) {
      wL += __shfl_xor(wL, off);
      wH += __shfl_xor(wH, off);
    }
    wsumL[r] = wL;
    wsumH[r] = wH;
  }
  const int b = bh >> 4, h = bh & 15;
#pragma unroll
  for (int n2 = 0; n2 < 4; ++n2) {
#pragma unroll
    for (int r = 0; r < 4; ++r) {
      const int hd = n2 * 16 + li;
      const int qL = qwL + 4 * g + r;
      const int qH = qwH + 4 * g + r;
      Zb[((size_t)(b * Sn + qL)) * Dn + h * HDn + hd] = f2bf(acczL[n2][r] / wsumL[r]);
      Zb[((size_t)(b * Sn + qH)) * Dn + h * HDn + hd] = f2bf(acczH[n2][r] / wsumH[r]);
    }
  }
#undef STAGE_A
#undef STAGE_B
}

// ---------------------------------------------------------------------------
extern "C" void kernel_launch(void* const* d_in, const int* in_sizes, int n_in,
                              void* d_out, int out_size, void* d_ws, size_t ws_size,
                              hipStream_t stream) {
  const float* query = (const float*)d_in[0];
  const float* key   = (const float*)d_in[1];
  const float* value = (const float*)d_in[2];
  const float* Wq = (const float*)d_in[4];
  const float* bq = (const float*)d_in[5];
  const float* Wk = (const float*)d_in[6];
  const float* bk = (const float*)d_in[7];
  const float* Wv = (const float*)d_in[8];
  const float* bv = (const float*)d_in[9];
  const float* Wo = (const float*)d_in[10];
  const float* bo = (const float*)d_in[11];

  char* ws = (char*)d_ws;
  const size_t MB = 1ull << 20;
  unsigned short* Wqt = (unsigned short*)(ws + 0 * MB);
  unsigned short* Wkt = (unsigned short*)(ws + 2 * MB);
  unsigned short* Wvt = (unsigned short*)(ws + 4 * MB);
  unsigned short* Wot = (unsigned short*)(ws + 6 * MB);
  float2* trig        = (float2*)(ws + 8 * MB);           // 512 KB
  unsigned short* Qa  = (unsigned short*)(ws + 9 * MB);   // bf16 activations
  unsigned short* Ka  = (unsigned short*)(ws + 17 * MB);
  unsigned short* Va  = (unsigned short*)(ws + 25 * MB);
  unsigned short* Qb  = (unsigned short*)(ws + 33 * MB);  // [b,h,s,hd] bf16 (Q prescaled)
  unsigned short* Kb  = (unsigned short*)(ws + 41 * MB);
  unsigned short* Qr  = (unsigned short*)(ws + 49 * MB);
  unsigned short* Kr  = (unsigned short*)(ws + 57 * MB);
  unsigned short* Vt  = (unsigned short*)(ws + 65 * MB);  // [b,h,hd,s] bf16
  unsigned short* Zb  = (unsigned short*)(ws + 73 * MB);  // [m][1024] bf16

  k_trig<<<256, 256, 0, stream>>>(trig);
  k_wtrans<<<dim3(16, 16, 4), 256, 0, stream>>>(Wq, Wk, Wv, Wo, Wqt, Wkt, Wvt, Wot);
  k_cvt<<<dim3(2048, 3), 256, 0, stream>>>(query, key, value, Qa, Ka, Va);
  k_gemm_proj<<<dim3(32, 8, 3), 256, 0, stream>>>(Qa, Ka, Va, Wqt, Wkt, Wvt,
                                                  bq, bk, bv, trig, Qb, Kb, Qr, Kr, Vt);
  k_attn<<<dim3(32, 16), 256, 0, stream>>>(Qr, Kr, Qb, Kb, Vt, Zb);
  k_gemm_out<<<dim3(64, 8), 256, 0, stream>>>(Zb, Wot, bo, (float*)d_out);
}